// Round 2
// baseline (5623.540 us; speedup 1.0000x reference)
//
#include <hip/hip_runtime.h>
#include <hip/hip_bf16.h>

#define NNODES 100000
#define DIN    256
#define NHID   128
#define EPS    1e-5f

// ---------------- GEMM: C[M][128] = A[M][K] @ W[K][128] (fp32) ----------------
template <int K>
__global__ __launch_bounds__(256) void gemm_kernel(const float* __restrict__ A,
                                                   const float* __restrict__ W,
                                                   float* __restrict__ C, int M) {
    const int BM = 64, BK = 32;
    __shared__ float As[BM][BK + 4];   // row stride 36 floats
    __shared__ float Bs[BK][NHID];

    const int t = threadIdx.x;
    const int tx = t & 31;   // col group: cols tx*4 .. tx*4+3
    const int ty = t >> 5;   // row group: rows ty*8 .. ty*8+7
    const int block_row = blockIdx.x * BM;

    float acc[8][4] = {};

    for (int k0 = 0; k0 < K; k0 += BK) {
        // Load A tile 64x32 (two halves of 32 rows), float4 per thread per half
        {
            const int r = t >> 3;            // 0..31
            const int kc = (t & 7) * 4;      // 0..28
#pragma unroll
            for (int i = 0; i < 2; ++i) {
                const int row = block_row + r + i * 32;
                float4 v = make_float4(0.f, 0.f, 0.f, 0.f);
                if (row < M)
                    v = *reinterpret_cast<const float4*>(A + (size_t)row * K + k0 + kc);
                *reinterpret_cast<float4*>(&As[r + i * 32][kc]) = v;
            }
        }
        // Load B tile 32x128 = 4096 floats; 256 threads * 4 float4
        {
#pragma unroll
            for (int i = 0; i < 4; ++i) {
                const int idx = i * 256 + t;       // 0..1023 float4 slots
                const int r = idx >> 5;            // 0..31
                const int c = (idx & 31) * 4;      // 0..124
                *reinterpret_cast<float4*>(&Bs[r][c]) =
                    *reinterpret_cast<const float4*>(W + (size_t)(k0 + r) * NHID + c);
            }
        }
        __syncthreads();

#pragma unroll
        for (int k = 0; k < BK; ++k) {
            float b[4];
            *reinterpret_cast<float4*>(b) = *reinterpret_cast<const float4*>(&Bs[k][tx * 4]);
#pragma unroll
            for (int i = 0; i < 8; ++i) {
                const float a = As[ty * 8 + i][k];
                acc[i][0] = fmaf(a, b[0], acc[i][0]);
                acc[i][1] = fmaf(a, b[1], acc[i][1]);
                acc[i][2] = fmaf(a, b[2], acc[i][2]);
                acc[i][3] = fmaf(a, b[3], acc[i][3]);
            }
        }
        __syncthreads();
    }

#pragma unroll
    for (int i = 0; i < 8; ++i) {
        const int row = block_row + ty * 8 + i;
        if (row < M)
            *reinterpret_cast<float4*>(C + (size_t)row * NHID + tx * 4) =
                *reinterpret_cast<float4*>(acc[i]);
    }
}

// ---------------- Edge scatter: agg[dst] += w * h[src], 32 threads/edge ----------------
__global__ __launch_bounds__(256) void scatter_kernel(const float* __restrict__ h,
                                                      const int* __restrict__ src,
                                                      const int* __restrict__ dst,
                                                      const float* __restrict__ w,
                                                      float* __restrict__ agg, int E) {
    const long long idx = (long long)blockIdx.x * 256 + threadIdx.x;
    const int e = (int)(idx >> 5);
    if (e >= E) return;
    const int f = ((int)idx & 31) * 4;
    const int s = src[e];
    const int d = dst[e];
    const float wt = w[e];
    const float4 v = *reinterpret_cast<const float4*>(h + (size_t)s * NHID + f);
    float* out = agg + (size_t)d * NHID + f;
    atomicAdd(out + 0, v.x * wt);
    atomicAdd(out + 1, v.y * wt);
    atomicAdd(out + 2, v.z * wt);
    atomicAdd(out + 3, v.w * wt);
}

// ---------------- BN stats: per-column sum and sum of squares ----------------
__global__ __launch_bounds__(256) void stats_kernel(const float* __restrict__ h,
                                                    float* __restrict__ sums, int nrows) {
    const int col = threadIdx.x & 127;
    const int half = threadIdx.x >> 7;
    float s = 0.f, sq = 0.f;
    for (int r = blockIdx.x * 2 + half; r < nrows; r += gridDim.x * 2) {
        const float v = h[(size_t)r * NHID + col];
        s += v;
        sq += v * v;
    }
    __shared__ float ls[256], lq[256];
    ls[threadIdx.x] = s;
    lq[threadIdx.x] = sq;
    __syncthreads();
    if (threadIdx.x < 128) {
        atomicAdd(&sums[col], ls[threadIdx.x] + ls[threadIdx.x + 128]);
        atomicAdd(&sums[128 + col], lq[threadIdx.x] + lq[threadIdx.x + 128]);
    }
}

// ---------------- BN finalize: scale/shift per column ----------------
__global__ void finalize_kernel(const float* __restrict__ sums,
                                const float* __restrict__ gamma,
                                const float* __restrict__ beta,
                                float* __restrict__ ss) {
    const int c = threadIdx.x;  // 128 threads
    const float invN = 1.0f / (float)NNODES;
    const float mean = sums[c] * invN;
    const float var = sums[128 + c] * invN - mean * mean;
    const float scale = gamma[c] * rsqrtf(var + EPS);
    ss[c] = scale;
    ss[128 + c] = beta[c] - mean * scale;
}

// ---------------- BN apply + ReLU (fp32 out) ----------------
__global__ __launch_bounds__(256) void apply_kernel(const float* __restrict__ in,
                                                    const float* __restrict__ ss,
                                                    float* __restrict__ out, int n4) {
    const int idx = blockIdx.x * 256 + threadIdx.x;
    if (idx >= n4) return;
    const int c = (idx & 31) * 4;
    const float4 v = reinterpret_cast<const float4*>(in)[idx];
    const float4 sc = *reinterpret_cast<const float4*>(ss + c);
    const float4 sh = *reinterpret_cast<const float4*>(ss + 128 + c);
    float4 r;
    r.x = fmaxf(fmaf(v.x, sc.x, sh.x), 0.f);
    r.y = fmaxf(fmaf(v.y, sc.y, sh.y), 0.f);
    r.z = fmaxf(fmaf(v.z, sc.z, sh.z), 0.f);
    r.w = fmaxf(fmaf(v.w, sc.w, sh.w), 0.f);
    reinterpret_cast<float4*>(out)[idx] = r;
}

extern "C" void kernel_launch(void* const* d_in, const int* in_sizes, int n_in,
                              void* d_out, int out_size, void* d_ws, size_t ws_size,
                              hipStream_t stream) {
    const float* x   = (const float*)d_in[0];
    const int*   ei  = (const int*)d_in[1];
    const float* ew  = (const float*)d_in[2];
    const float* W1  = (const float*)d_in[3];
    const float* g1  = (const float*)d_in[5];
    const float* be1 = (const float*)d_in[6];
    const float* W2  = (const float*)d_in[7];
    const float* g2  = (const float*)d_in[9];
    const float* be2 = (const float*)d_in[10];
    float* out = (float*)d_out;   // reference output dtype is float32

    const int M = NNODES;
    const int E = in_sizes[2];
    const int* src = ei;
    const int* dst = ei + E;

    float* A    = (float*)d_ws;                       // M*128 fp32
    float* B    = A + (size_t)M * NHID;               // M*128 fp32
    float* sums = B + (size_t)M * NHID;               // 256 fp32
    float* ss   = sums + 256;                         // 256 fp32

    const int gemm_grid = (M + 63) / 64;
    const int scat_grid = (int)(((long long)E * 32 + 255) / 256);
    const int n4 = M * NHID / 4;
    const int app_grid = (n4 + 255) / 256;

    // ---- Layer 1 ----
    gemm_kernel<DIN><<<gemm_grid, 256, 0, stream>>>(x, W1, A, M);
    hipMemsetAsync(B, 0, (size_t)M * NHID * sizeof(float), stream);
    scatter_kernel<<<scat_grid, 256, 0, stream>>>(A, src, dst, ew, B, E);
    hipMemsetAsync(sums, 0, 256 * sizeof(float), stream);
    stats_kernel<<<1024, 256, 0, stream>>>(B, sums, M);
    finalize_kernel<<<1, 128, 0, stream>>>(sums, g1, be1, ss);
    apply_kernel<<<app_grid, 256, 0, stream>>>(B, ss, A, n4);   // h1 -> A

    // ---- Layer 2 ----
    gemm_kernel<NHID><<<gemm_grid, 256, 0, stream>>>(A, W2, B, M);
    hipMemsetAsync(A, 0, (size_t)M * NHID * sizeof(float), stream);
    scatter_kernel<<<scat_grid, 256, 0, stream>>>(B, src, dst, ew, A, E);
    hipMemsetAsync(sums, 0, 256 * sizeof(float), stream);
    stats_kernel<<<1024, 256, 0, stream>>>(A, sums, M);
    finalize_kernel<<<1, 128, 0, stream>>>(sums, g2, be2, ss);
    apply_kernel<<<app_grid, 256, 0, stream>>>(A, ss, out, n4);  // fp32 final output
}

// Round 3
// 690.814 us; speedup vs baseline: 8.1405x; 8.1405x over previous
//
#include <hip/hip_runtime.h>
#include <hip/hip_bf16.h>

#define NNODES 100000
#define DIN    256
#define NHID   128
#define EPS    1e-5f
#define SCAN_CHUNK 1024

// ---------------- GEMM: C[M][128] = A[M][K] @ W[K][128] (fp32) ----------------
template <int K>
__global__ __launch_bounds__(256) void gemm_kernel(const float* __restrict__ A,
                                                   const float* __restrict__ W,
                                                   float* __restrict__ C, int M) {
    const int BM = 64, BK = 32;
    __shared__ float As[BM][BK + 4];
    __shared__ float Bs[BK][NHID];

    const int t = threadIdx.x;
    const int tx = t & 31;
    const int ty = t >> 5;
    const int block_row = blockIdx.x * BM;

    float acc[8][4] = {};

    for (int k0 = 0; k0 < K; k0 += BK) {
        {
            const int r = t >> 3;
            const int kc = (t & 7) * 4;
#pragma unroll
            for (int i = 0; i < 2; ++i) {
                const int row = block_row + r + i * 32;
                float4 v = make_float4(0.f, 0.f, 0.f, 0.f);
                if (row < M)
                    v = *reinterpret_cast<const float4*>(A + (size_t)row * K + k0 + kc);
                *reinterpret_cast<float4*>(&As[r + i * 32][kc]) = v;
            }
        }
        {
#pragma unroll
            for (int i = 0; i < 4; ++i) {
                const int idx = i * 256 + t;
                const int r = idx >> 5;
                const int c = (idx & 31) * 4;
                *reinterpret_cast<float4*>(&Bs[r][c]) =
                    *reinterpret_cast<const float4*>(W + (size_t)(k0 + r) * NHID + c);
            }
        }
        __syncthreads();

#pragma unroll
        for (int k = 0; k < BK; ++k) {
            float b[4];
            *reinterpret_cast<float4*>(b) = *reinterpret_cast<const float4*>(&Bs[k][tx * 4]);
#pragma unroll
            for (int i = 0; i < 8; ++i) {
                const float a = As[ty * 8 + i][k];
                acc[i][0] = fmaf(a, b[0], acc[i][0]);
                acc[i][1] = fmaf(a, b[1], acc[i][1]);
                acc[i][2] = fmaf(a, b[2], acc[i][2]);
                acc[i][3] = fmaf(a, b[3], acc[i][3]);
            }
        }
        __syncthreads();
    }

#pragma unroll
    for (int i = 0; i < 8; ++i) {
        const int row = block_row + ty * 8 + i;
        if (row < M)
            *reinterpret_cast<float4*>(C + (size_t)row * NHID + tx * 4) =
                *reinterpret_cast<float4*>(acc[i]);
    }
}

// ---------------- CSR build ----------------
__global__ __launch_bounds__(256) void hist_kernel(const int* __restrict__ dst,
                                                   int* __restrict__ counts, int E) {
    const int e = blockIdx.x * 256 + threadIdx.x;
    if (e < E) atomicAdd(&counts[dst[e]], 1);
}

__global__ __launch_bounds__(1024) void scan1_kernel(const int* __restrict__ counts,
                                                     int* __restrict__ row_ptr,
                                                     int* __restrict__ bsum, int n) {
    __shared__ int sh[SCAN_CHUNK];
    const int g = blockIdx.x * SCAN_CHUNK + threadIdx.x;
    sh[threadIdx.x] = (g < n) ? counts[g] : 0;
    __syncthreads();
#pragma unroll
    for (int off = 1; off < SCAN_CHUNK; off <<= 1) {
        const int t = (threadIdx.x >= off) ? sh[threadIdx.x - off] : 0;
        __syncthreads();
        sh[threadIdx.x] += t;
        __syncthreads();
    }
    if (g < n) row_ptr[g + 1] = sh[threadIdx.x];
    if (threadIdx.x == SCAN_CHUNK - 1) bsum[blockIdx.x] = sh[SCAN_CHUNK - 1];
}

__global__ void scan2_kernel(int* __restrict__ bsum, int nchunks) {
    // single thread: exclusive scan of chunk totals (nchunks ~ 98)
    if (threadIdx.x == 0 && blockIdx.x == 0) {
        int run = 0;
        for (int i = 0; i < nchunks; ++i) {
            const int t = bsum[i];
            bsum[i] = run;
            run += t;
        }
    }
}

__global__ __launch_bounds__(256) void scan3_kernel(int* __restrict__ row_ptr,
                                                    const int* __restrict__ bsum, int n) {
    const int g = blockIdx.x * 256 + threadIdx.x;
    if (g < n) row_ptr[g + 1] += bsum[g >> 10];
    if (g == 0) row_ptr[0] = 0;
}

__global__ __launch_bounds__(256) void copy_kernel(const int* __restrict__ row_ptr,
                                                   int* __restrict__ cursor, int n) {
    const int g = blockIdx.x * 256 + threadIdx.x;
    if (g < n) cursor[g] = row_ptr[g];
}

__global__ __launch_bounds__(256) void fill_kernel(const int* __restrict__ src,
                                                   const int* __restrict__ dst,
                                                   const float* __restrict__ w,
                                                   int* __restrict__ cursor,
                                                   int* __restrict__ s_src,
                                                   float* __restrict__ s_w, int E) {
    const int e = blockIdx.x * 256 + threadIdx.x;
    if (e < E) {
        const int pos = atomicAdd(&cursor[dst[e]], 1);
        s_src[pos] = src[e];
        s_w[pos] = w[e];
    }
}

// ---------------- Aggregate: one wave per node, gather h[src]*w, no atomics ----------------
__global__ __launch_bounds__(256) void aggregate_kernel(const float* __restrict__ h,
                                                        const int* __restrict__ row_ptr,
                                                        const int* __restrict__ s_src,
                                                        const float* __restrict__ s_w,
                                                        float* __restrict__ out, int n) {
    const int wid = (blockIdx.x * 256 + threadIdx.x) >> 6;  // node = global wave id
    if (wid >= n) return;
    const int lane = threadIdx.x & 63;
    const int beg = row_ptr[wid];
    const int end = row_ptr[wid + 1];
    const int foff = lane * 2;

    float ax = 0.f, ay = 0.f;
    int j = beg;
    for (; j + 2 <= end; j += 2) {
        const int s0 = s_src[j];
        const int s1 = s_src[j + 1];
        const float w0 = s_w[j];
        const float w1 = s_w[j + 1];
        const float2 v0 = *reinterpret_cast<const float2*>(h + (size_t)s0 * NHID + foff);
        const float2 v1 = *reinterpret_cast<const float2*>(h + (size_t)s1 * NHID + foff);
        ax += w0 * v0.x + w1 * v1.x;
        ay += w0 * v0.y + w1 * v1.y;
    }
    if (j < end) {
        const int s0 = s_src[j];
        const float w0 = s_w[j];
        const float2 v0 = *reinterpret_cast<const float2*>(h + (size_t)s0 * NHID + foff);
        ax += w0 * v0.x;
        ay += w0 * v0.y;
    }
    float2 r;
    r.x = ax;
    r.y = ay;
    *reinterpret_cast<float2*>(out + (size_t)wid * NHID + foff) = r;
}

// ---------------- BN stats / finalize / apply ----------------
__global__ __launch_bounds__(256) void stats_kernel(const float* __restrict__ h,
                                                    float* __restrict__ sums, int nrows) {
    const int col = threadIdx.x & 127;
    const int half = threadIdx.x >> 7;
    float s = 0.f, sq = 0.f;
    for (int r = blockIdx.x * 2 + half; r < nrows; r += gridDim.x * 2) {
        const float v = h[(size_t)r * NHID + col];
        s += v;
        sq += v * v;
    }
    __shared__ float ls[256], lq[256];
    ls[threadIdx.x] = s;
    lq[threadIdx.x] = sq;
    __syncthreads();
    if (threadIdx.x < 128) {
        atomicAdd(&sums[col], ls[threadIdx.x] + ls[threadIdx.x + 128]);
        atomicAdd(&sums[128 + col], lq[threadIdx.x] + lq[threadIdx.x + 128]);
    }
}

__global__ void finalize_kernel(const float* __restrict__ sums,
                                const float* __restrict__ gamma,
                                const float* __restrict__ beta,
                                float* __restrict__ ss) {
    const int c = threadIdx.x;
    const float invN = 1.0f / (float)NNODES;
    const float mean = sums[c] * invN;
    const float var = sums[128 + c] * invN - mean * mean;
    const float scale = gamma[c] * rsqrtf(var + EPS);
    ss[c] = scale;
    ss[128 + c] = beta[c] - mean * scale;
}

__global__ __launch_bounds__(256) void apply_kernel(const float* __restrict__ in,
                                                    const float* __restrict__ ss,
                                                    float* __restrict__ out, int n4) {
    const int idx = blockIdx.x * 256 + threadIdx.x;
    if (idx >= n4) return;
    const int c = (idx & 31) * 4;
    const float4 v = reinterpret_cast<const float4*>(in)[idx];
    const float4 sc = *reinterpret_cast<const float4*>(ss + c);
    const float4 sh = *reinterpret_cast<const float4*>(ss + 128 + c);
    float4 r;
    r.x = fmaxf(fmaf(v.x, sc.x, sh.x), 0.f);
    r.y = fmaxf(fmaf(v.y, sc.y, sh.y), 0.f);
    r.z = fmaxf(fmaf(v.z, sc.z, sh.z), 0.f);
    r.w = fmaxf(fmaf(v.w, sc.w, sh.w), 0.f);
    reinterpret_cast<float4*>(out)[idx] = r;
}

extern "C" void kernel_launch(void* const* d_in, const int* in_sizes, int n_in,
                              void* d_out, int out_size, void* d_ws, size_t ws_size,
                              hipStream_t stream) {
    const float* x   = (const float*)d_in[0];
    const int*   ei  = (const int*)d_in[1];
    const float* ew  = (const float*)d_in[2];
    const float* W1  = (const float*)d_in[3];
    const float* g1  = (const float*)d_in[5];
    const float* be1 = (const float*)d_in[6];
    const float* W2  = (const float*)d_in[7];
    const float* g2  = (const float*)d_in[9];
    const float* be2 = (const float*)d_in[10];
    float* out = (float*)d_out;

    const int M = NNODES;
    const int E = in_sizes[2];
    const int* src = ei;
    const int* dst = ei + E;

    // workspace layout
    float* A    = (float*)d_ws;                         // M*128 fp32
    float* B    = A + (size_t)M * NHID;                 // M*128 fp32
    float* sums = B + (size_t)M * NHID;                 // 256
    float* ss   = sums + 256;                           // 256
    int* row_ptr = (int*)(ss + 256);                    // M+1
    int* cursor  = row_ptr + (M + 1);                   // M
    int* bsum    = cursor + M;                          // 128
    int* s_src   = bsum + 128;                          // E
    float* s_w   = (float*)(s_src + E);                 // E

    const int gemm_grid = (M + 63) / 64;
    const int n4 = M * NHID / 4;
    const int app_grid = (n4 + 255) / 256;
    const int egrid = (E + 255) / 256;
    const int ngrid = (M + 255) / 256;
    const int nchunks = (M + SCAN_CHUNK - 1) / SCAN_CHUNK;
    const int agg_grid = (M * 64 + 255) / 256;  // one wave per node, 4 waves/block

    // ---- CSR build (shared by both layers) ----
    hipMemsetAsync(cursor, 0, (size_t)M * sizeof(int), stream);
    hist_kernel<<<egrid, 256, 0, stream>>>(dst, cursor, E);
    scan1_kernel<<<nchunks, SCAN_CHUNK, 0, stream>>>(cursor, row_ptr, bsum, M);
    scan2_kernel<<<1, 64, 0, stream>>>(bsum, nchunks);
    scan3_kernel<<<ngrid, 256, 0, stream>>>(row_ptr, bsum, M);
    copy_kernel<<<ngrid, 256, 0, stream>>>(row_ptr, cursor, M);
    fill_kernel<<<egrid, 256, 0, stream>>>(src, dst, ew, cursor, s_src, s_w, E);

    // ---- Layer 1 ----
    gemm_kernel<DIN><<<gemm_grid, 256, 0, stream>>>(x, W1, A, M);
    aggregate_kernel<<<agg_grid, 256, 0, stream>>>(A, row_ptr, s_src, s_w, B, M);
    hipMemsetAsync(sums, 0, 256 * sizeof(float), stream);
    stats_kernel<<<1024, 256, 0, stream>>>(B, sums, M);
    finalize_kernel<<<1, 128, 0, stream>>>(sums, g1, be1, ss);
    apply_kernel<<<app_grid, 256, 0, stream>>>(B, ss, A, n4);   // h1 -> A

    // ---- Layer 2 ----
    gemm_kernel<NHID><<<gemm_grid, 256, 0, stream>>>(A, W2, B, M);
    aggregate_kernel<<<agg_grid, 256, 0, stream>>>(B, row_ptr, s_src, s_w, A, M);
    hipMemsetAsync(sums, 0, 256 * sizeof(float), stream);
    stats_kernel<<<1024, 256, 0, stream>>>(A, sums, M);
    finalize_kernel<<<1, 128, 0, stream>>>(sums, g2, be2, ss);
    apply_kernel<<<app_grid, 256, 0, stream>>>(A, ss, out, n4);
}

// Round 4
// 546.186 us; speedup vs baseline: 10.2960x; 1.2648x over previous
//
#include <hip/hip_runtime.h>
#include <hip/hip_bf16.h>

#define NNODES 100000
#define DIN    256
#define NHID   128
#define EPS    1e-5f
#define SCAN_CHUNK 1024

typedef __attribute__((ext_vector_type(8))) short short8v;  // 8 x bf16 (4 VGPR)
typedef __attribute__((ext_vector_type(4))) float f32x4;

static __device__ __forceinline__ unsigned short f2bf(float v) {
    __hip_bfloat16 b = __float2bfloat16(v);
    return *reinterpret_cast<unsigned short*>(&b);
}
static __device__ __forceinline__ float bfhi2f(unsigned int u) {  // high 16 bits as bf16
    union { unsigned int i; float f; } x;
    x.i = u & 0xFFFF0000u;
    return x.f;
}
static __device__ __forceinline__ float bflo2f(unsigned int u) {  // low 16 bits as bf16
    union { unsigned int i; float f; } x;
    x.i = u << 16;
    return x.f;
}

// ---------------- MFMA GEMM: C[M][128] = A[M][K] @ W[K][128], bf16 in / fp32 acc / bf16 out ----
// W (fp32, K x 128) is transposed+converted into padded LDS once per block.
// A fragments load directly from global (each row read exactly once across the grid).
template <int K, bool AF32>
__global__ __launch_bounds__(256) void mfma_gemm(const float* __restrict__ Af,
                                                 const unsigned short* __restrict__ Ab,
                                                 const float* __restrict__ W,
                                                 unsigned short* __restrict__ C, int M) {
    constexpr int LDW = K + 8;                 // padded k-stride (elements)
    __shared__ unsigned short Wt[128 * LDW];   // Wt[col][k]

    const int t = threadIdx.x;
    for (int i = t; i < K * 128; i += 256) {
        const int k = i >> 7;       // W row
        const int c = i & 127;      // W col
        Wt[c * LDW + k] = f2bf(W[i]);
    }

    const int wid = t >> 6;
    const int lane = t & 63;
    const int wr = wid >> 1, wc = wid & 1;
    const int l15 = lane & 15, g = lane >> 4;
    const int R0 = blockIdx.x * 128 + wr * 64;

    f32x4 acc[4][4] = {};
    __syncthreads();

    for (int s = 0; s < K / 32; ++s) {
        short8v b[4];
#pragma unroll
        for (int n = 0; n < 4; ++n) {
            const int col = wc * 64 + n * 16 + l15;
            b[n] = *reinterpret_cast<const short8v*>(&Wt[col * LDW + s * 32 + g * 8]);
        }
        short8v a[4];
#pragma unroll
        for (int m = 0; m < 4; ++m) {
            int row = R0 + m * 16 + l15;
            row = row < M ? row : M - 1;   // clamp; results for pad rows discarded
            if constexpr (AF32) {
                const float* p = Af + (size_t)row * K + s * 32 + g * 8;
                const float4 v0 = *reinterpret_cast<const float4*>(p);
                const float4 v1 = *reinterpret_cast<const float4*>(p + 4);
                short8v av;
                av[0] = (short)f2bf(v0.x); av[1] = (short)f2bf(v0.y);
                av[2] = (short)f2bf(v0.z); av[3] = (short)f2bf(v0.w);
                av[4] = (short)f2bf(v1.x); av[5] = (short)f2bf(v1.y);
                av[6] = (short)f2bf(v1.z); av[7] = (short)f2bf(v1.w);
                a[m] = av;
            } else {
                a[m] = *reinterpret_cast<const short8v*>(Ab + (size_t)row * K + s * 32 + g * 8);
            }
        }
#pragma unroll
        for (int m = 0; m < 4; ++m)
#pragma unroll
            for (int n = 0; n < 4; ++n)
                acc[m][n] = __builtin_amdgcn_mfma_f32_16x16x32_bf16(a[m], b[n], acc[m][n], 0, 0, 0);
    }

    // C/D layout (verified): col = lane&15, row = (lane>>4)*4 + q
#pragma unroll
    for (int m = 0; m < 4; ++m) {
#pragma unroll
        for (int q = 0; q < 4; ++q) {
            const int row = R0 + m * 16 + g * 4 + q;
            if (row < M) {
                unsigned short* cp = C + (size_t)row * NHID + wc * 64 + l15;
#pragma unroll
                for (int n = 0; n < 4; ++n)
                    cp[n * 16] = f2bf(acc[m][n][q]);
            }
        }
    }
}

// ---------------- CSR build ----------------
__global__ __launch_bounds__(256) void hist_kernel(const int* __restrict__ dst,
                                                   int* __restrict__ counts, int E) {
    const int e = blockIdx.x * 256 + threadIdx.x;
    if (e < E) atomicAdd(&counts[dst[e]], 1);
}

__global__ __launch_bounds__(1024) void scan1_kernel(const int* __restrict__ counts,
                                                     int* __restrict__ row_ptr,
                                                     int* __restrict__ bsum, int n) {
    __shared__ int sh[SCAN_CHUNK];
    const int g = blockIdx.x * SCAN_CHUNK + threadIdx.x;
    sh[threadIdx.x] = (g < n) ? counts[g] : 0;
    __syncthreads();
#pragma unroll
    for (int off = 1; off < SCAN_CHUNK; off <<= 1) {
        const int t = (threadIdx.x >= off) ? sh[threadIdx.x - off] : 0;
        __syncthreads();
        sh[threadIdx.x] += t;
        __syncthreads();
    }
    if (g < n) row_ptr[g + 1] = sh[threadIdx.x];
    if (threadIdx.x == SCAN_CHUNK - 1) bsum[blockIdx.x] = sh[SCAN_CHUNK - 1];
}

__global__ void scan2_kernel(int* __restrict__ bsum, int nchunks) {
    if (threadIdx.x == 0 && blockIdx.x == 0) {
        int run = 0;
        for (int i = 0; i < nchunks; ++i) {
            const int t = bsum[i];
            bsum[i] = run;
            run += t;
        }
    }
}

// adds chunk offsets AND initializes cursor = exclusive row starts (fused copy)
__global__ __launch_bounds__(256) void scan3_kernel(int* __restrict__ row_ptr,
                                                    const int* __restrict__ bsum,
                                                    int* __restrict__ cursor, int n) {
    const int g = blockIdx.x * 256 + threadIdx.x;
    if (g < n) {
        const int v = row_ptr[g + 1] + bsum[g >> 10];
        row_ptr[g + 1] = v;
        if (g + 1 < n) cursor[g + 1] = v;
    }
    if (g == 0) { row_ptr[0] = 0; cursor[0] = 0; }
}

__global__ __launch_bounds__(256) void fill_kernel(const int* __restrict__ src,
                                                   const int* __restrict__ dst,
                                                   const float* __restrict__ w,
                                                   int* __restrict__ cursor,
                                                   int2* __restrict__ s_iw, int E) {
    const int e = blockIdx.x * 256 + threadIdx.x;
    if (e < E) {
        const int pos = atomicAdd(&cursor[dst[e]], 1);
        int2 p;
        p.x = src[e];
        p.y = __float_as_int(w[e]);
        s_iw[pos] = p;
    }
}

// ---------------- Aggregate: one wave per node, bf16 gather, fp32 accumulate ----------------
__global__ __launch_bounds__(256) void aggregate_kernel(const unsigned short* __restrict__ hb,
                                                        const int* __restrict__ row_ptr,
                                                        const int2* __restrict__ s_iw,
                                                        float* __restrict__ out, int n) {
    const int wid = (blockIdx.x * 256 + threadIdx.x) >> 6;
    if (wid >= n) return;
    const int lane = threadIdx.x & 63;
    const int beg = row_ptr[wid];
    const int end = row_ptr[wid + 1];
    const int boff = lane * 2;   // cols 2*lane, 2*lane+1

    float ax = 0.f, ay = 0.f;
    int j = beg;
    for (; j + 4 <= end; j += 4) {
        const int2 e0 = s_iw[j], e1 = s_iw[j + 1], e2 = s_iw[j + 2], e3 = s_iw[j + 3];
        const unsigned int v0 = *reinterpret_cast<const unsigned int*>(hb + (size_t)e0.x * NHID + boff);
        const unsigned int v1 = *reinterpret_cast<const unsigned int*>(hb + (size_t)e1.x * NHID + boff);
        const unsigned int v2 = *reinterpret_cast<const unsigned int*>(hb + (size_t)e2.x * NHID + boff);
        const unsigned int v3 = *reinterpret_cast<const unsigned int*>(hb + (size_t)e3.x * NHID + boff);
        const float w0 = __int_as_float(e0.y), w1 = __int_as_float(e1.y);
        const float w2 = __int_as_float(e2.y), w3 = __int_as_float(e3.y);
        ax = fmaf(w0, bflo2f(v0), ax); ay = fmaf(w0, bfhi2f(v0), ay);
        ax = fmaf(w1, bflo2f(v1), ax); ay = fmaf(w1, bfhi2f(v1), ay);
        ax = fmaf(w2, bflo2f(v2), ax); ay = fmaf(w2, bfhi2f(v2), ay);
        ax = fmaf(w3, bflo2f(v3), ax); ay = fmaf(w3, bfhi2f(v3), ay);
    }
    for (; j < end; ++j) {
        const int2 e0 = s_iw[j];
        const unsigned int v0 = *reinterpret_cast<const unsigned int*>(hb + (size_t)e0.x * NHID + boff);
        const float w0 = __int_as_float(e0.y);
        ax = fmaf(w0, bflo2f(v0), ax);
        ay = fmaf(w0, bfhi2f(v0), ay);
    }
    float2 r;
    r.x = ax;
    r.y = ay;
    *reinterpret_cast<float2*>(out + (size_t)wid * NHID + boff) = r;
}

// ---------------- BN stats / finalize / apply ----------------
__global__ __launch_bounds__(256) void stats_kernel(const float* __restrict__ h,
                                                    float* __restrict__ sums, int nrows) {
    const int col = threadIdx.x & 127;
    const int half = threadIdx.x >> 7;
    float s = 0.f, sq = 0.f;
    for (int r = blockIdx.x * 2 + half; r < nrows; r += gridDim.x * 2) {
        const float v = h[(size_t)r * NHID + col];
        s += v;
        sq += v * v;
    }
    __shared__ float ls[256], lq[256];
    ls[threadIdx.x] = s;
    lq[threadIdx.x] = sq;
    __syncthreads();
    if (threadIdx.x < 128) {
        atomicAdd(&sums[col], ls[threadIdx.x] + ls[threadIdx.x + 128]);
        atomicAdd(&sums[128 + col], lq[threadIdx.x] + lq[threadIdx.x + 128]);
    }
}

__global__ void finalize_kernel(const float* __restrict__ sums,
                                const float* __restrict__ gamma,
                                const float* __restrict__ beta,
                                float* __restrict__ ss) {
    const int c = threadIdx.x;
    const float invN = 1.0f / (float)NNODES;
    const float mean = sums[c] * invN;
    const float var = sums[128 + c] * invN - mean * mean;
    const float scale = gamma[c] * rsqrtf(var + EPS);
    ss[c] = scale;
    ss[128 + c] = beta[c] - mean * scale;
}

// BN+ReLU -> bf16 (layer-1 hidden, feeds GEMM2)
__global__ __launch_bounds__(256) void apply_bf16_kernel(const float* __restrict__ in,
                                                         const float* __restrict__ ss,
                                                         unsigned short* __restrict__ out, int n4) {
    const int idx = blockIdx.x * 256 + threadIdx.x;
    if (idx >= n4) return;
    const int c = (idx & 31) * 4;
    const float4 v = reinterpret_cast<const float4*>(in)[idx];
    const float4 sc = *reinterpret_cast<const float4*>(ss + c);
    const float4 sh = *reinterpret_cast<const float4*>(ss + 128 + c);
    ushort4 r;
    r.x = f2bf(fmaxf(fmaf(v.x, sc.x, sh.x), 0.f));
    r.y = f2bf(fmaxf(fmaf(v.y, sc.y, sh.y), 0.f));
    r.z = f2bf(fmaxf(fmaf(v.z, sc.z, sh.z), 0.f));
    r.w = f2bf(fmaxf(fmaf(v.w, sc.w, sh.w), 0.f));
    *reinterpret_cast<ushort4*>(out + (size_t)idx * 4) = r;
}

// BN+ReLU -> fp32 (final output)
__global__ __launch_bounds__(256) void apply_f32_kernel(const float* __restrict__ in,
                                                        const float* __restrict__ ss,
                                                        float* __restrict__ out, int n4) {
    const int idx = blockIdx.x * 256 + threadIdx.x;
    if (idx >= n4) return;
    const int c = (idx & 31) * 4;
    const float4 v = reinterpret_cast<const float4*>(in)[idx];
    const float4 sc = *reinterpret_cast<const float4*>(ss + c);
    const float4 sh = *reinterpret_cast<const float4*>(ss + 128 + c);
    float4 r;
    r.x = fmaxf(fmaf(v.x, sc.x, sh.x), 0.f);
    r.y = fmaxf(fmaf(v.y, sc.y, sh.y), 0.f);
    r.z = fmaxf(fmaf(v.z, sc.z, sh.z), 0.f);
    r.w = fmaxf(fmaf(v.w, sc.w, sh.w), 0.f);
    reinterpret_cast<float4*>(out)[idx] = r;
}

extern "C" void kernel_launch(void* const* d_in, const int* in_sizes, int n_in,
                              void* d_out, int out_size, void* d_ws, size_t ws_size,
                              hipStream_t stream) {
    const float* x   = (const float*)d_in[0];
    const int*   ei  = (const int*)d_in[1];
    const float* ew  = (const float*)d_in[2];
    const float* W1  = (const float*)d_in[3];
    const float* g1  = (const float*)d_in[5];
    const float* be1 = (const float*)d_in[6];
    const float* W2  = (const float*)d_in[7];
    const float* g2  = (const float*)d_in[9];
    const float* be2 = (const float*)d_in[10];
    float* out = (float*)d_out;

    const int M = NNODES;
    const int E = in_sizes[2];
    const int* src = ei;
    const int* dst = ei + E;

    // workspace layout (~116 MB)
    unsigned short* hb  = (unsigned short*)d_ws;            // M*128 bf16 (gather table; reused L1/L2)
    float* agg          = (float*)(hb + (size_t)M * NHID);  // M*128 fp32
    unsigned short* h1b = (unsigned short*)(agg + (size_t)M * NHID);  // M*128 bf16
    float* sums         = (float*)(h1b + (size_t)M * NHID); // 256
    float* ss           = sums + 256;                       // 256
    int* row_ptr        = (int*)(ss + 256);                 // M+1
    int* cursor         = row_ptr + (M + 1);                // M
    int* bsum           = cursor + M + 1;                   // 128 (+1 pad keeps s_iw 8B-aligned)
    int2* s_iw          = (int2*)(bsum + 128);              // E

    const int gemm_grid = (M + 127) / 128;
    const int n4 = M * NHID / 4;
    const int app_grid = (n4 + 255) / 256;
    const int egrid = (E + 255) / 256;
    const int ngrid = (M + 255) / 256;
    const int nchunks = (M + SCAN_CHUNK - 1) / SCAN_CHUNK;
    const int agg_grid = (M * 64 + 255) / 256;

    // ---- CSR build (shared by both layers) ----
    hipMemsetAsync(cursor, 0, (size_t)M * sizeof(int), stream);
    hist_kernel<<<egrid, 256, 0, stream>>>(dst, cursor, E);
    scan1_kernel<<<nchunks, SCAN_CHUNK, 0, stream>>>(cursor, row_ptr, bsum, M);
    scan2_kernel<<<1, 64, 0, stream>>>(bsum, nchunks);
    scan3_kernel<<<ngrid, 256, 0, stream>>>(row_ptr, bsum, cursor, M);
    fill_kernel<<<egrid, 256, 0, stream>>>(src, dst, ew, cursor, s_iw, E);

    // ---- Layer 1 ----
    mfma_gemm<DIN, true><<<gemm_grid, 256, 0, stream>>>(x, nullptr, W1, hb, M);
    aggregate_kernel<<<agg_grid, 256, 0, stream>>>(hb, row_ptr, s_iw, agg, M);
    hipMemsetAsync(sums, 0, 256 * sizeof(float), stream);
    stats_kernel<<<1024, 256, 0, stream>>>(agg, sums, M);
    finalize_kernel<<<1, 128, 0, stream>>>(sums, g1, be1, ss);
    apply_bf16_kernel<<<app_grid, 256, 0, stream>>>(agg, ss, h1b, n4);

    // ---- Layer 2 ----
    mfma_gemm<NHID, false><<<gemm_grid, 256, 0, stream>>>(nullptr, h1b, W2, hb, M);
    aggregate_kernel<<<agg_grid, 256, 0, stream>>>(hb, row_ptr, s_iw, agg, M);
    hipMemsetAsync(sums, 0, 256 * sizeof(float), stream);
    stats_kernel<<<1024, 256, 0, stream>>>(agg, sums, M);
    finalize_kernel<<<1, 128, 0, stream>>>(sums, g2, be2, ss);
    apply_f32_kernel<<<app_grid, 256, 0, stream>>>(agg, ss, out, n4);
}

// Round 5
// 443.043 us; speedup vs baseline: 12.6930x; 1.2328x over previous
//
#include <hip/hip_runtime.h>
#include <hip/hip_bf16.h>

#define NNODES 100000
#define DIN    256
#define NHID   128
#define EPS    1e-5f
#define NB     ((NNODES + 255) >> 8)   // 391 buckets of 256 dst nodes
#define BCAP   5120                    // per-bucket capacity (mean ~4092, +16 sigma)
#define CURPAD 16                      // bucket counters padded to 64B (L2-slice spread)

typedef __attribute__((ext_vector_type(8))) short short8v;  // 8 x bf16
typedef __attribute__((ext_vector_type(4))) float f32x4;

static __device__ __forceinline__ unsigned short f2bf(float v) {
    __hip_bfloat16 b = __float2bfloat16(v);
    return *reinterpret_cast<unsigned short*>(&b);
}
static __device__ __forceinline__ float bfhi2f(unsigned int u) {
    union { unsigned int i; float f; } x; x.i = u & 0xFFFF0000u; return x.f;
}
static __device__ __forceinline__ float bflo2f(unsigned int u) {
    union { unsigned int i; float f; } x; x.i = u << 16; return x.f;
}

// ---------------- MFMA GEMM: C[M][128] = A[M][K] @ W[K][128] ----------------
// MODE 0: A fp32, direct bf16 convert (layer-1: A = x)
// MODE 1: A fp32 + fused BN(scale/shift from SS)+ReLU before convert (layer-2: A = agg)
template <int K, int MODE>
__global__ __launch_bounds__(256) void mfma_gemm(const float* __restrict__ Af,
                                                 const float* __restrict__ W,
                                                 const float* __restrict__ SS,
                                                 unsigned short* __restrict__ C, int M) {
    constexpr int LDW = K + 8;
    __shared__ unsigned short Wt[128 * LDW];   // W transposed: Wt[col][k]
    __shared__ float ssl[256];

    const int t = threadIdx.x;
    for (int i = t; i < K * 128; i += 256) {
        const int k = i >> 7;
        const int c = i & 127;
        Wt[c * LDW + k] = f2bf(W[i]);
    }
    if (MODE == 1 && t < 256) ssl[t] = SS[t];

    const int wid = t >> 6;
    const int lane = t & 63;
    const int wr = wid >> 1, wc = wid & 1;
    const int l15 = lane & 15, g = lane >> 4;
    const int R0 = blockIdx.x * 128 + wr * 64;

    f32x4 acc[4][4] = {};
    __syncthreads();

    for (int s = 0; s < K / 32; ++s) {
        short8v b[4];
#pragma unroll
        for (int n = 0; n < 4; ++n) {
            const int col = wc * 64 + n * 16 + l15;
            b[n] = *reinterpret_cast<const short8v*>(&Wt[col * LDW + s * 32 + g * 8]);
        }
        float sc[8], sh[8];
        if (MODE == 1) {
#pragma unroll
            for (int j = 0; j < 8; ++j) {
                sc[j] = ssl[s * 32 + g * 8 + j];
                sh[j] = ssl[128 + s * 32 + g * 8 + j];
            }
        }
        short8v a[4];
#pragma unroll
        for (int m = 0; m < 4; ++m) {
            int row = R0 + m * 16 + l15;
            row = row < M ? row : M - 1;   // clamp; pad rows discarded at store
            const float* p = Af + (size_t)row * K + s * 32 + g * 8;
            const float4 v0 = *reinterpret_cast<const float4*>(p);
            const float4 v1 = *reinterpret_cast<const float4*>(p + 4);
            float vv[8] = {v0.x, v0.y, v0.z, v0.w, v1.x, v1.y, v1.z, v1.w};
            short8v av;
#pragma unroll
            for (int j = 0; j < 8; ++j) {
                float y = vv[j];
                if (MODE == 1) y = fmaxf(fmaf(y, sc[j], sh[j]), 0.f);
                av[j] = (short)f2bf(y);
            }
            a[m] = av;
        }
#pragma unroll
        for (int m = 0; m < 4; ++m)
#pragma unroll
            for (int n = 0; n < 4; ++n)
                acc[m][n] = __builtin_amdgcn_mfma_f32_16x16x32_bf16(a[m], b[n], acc[m][n], 0, 0, 0);
    }

    // C/D layout: col = lane&15, row = (lane>>4)*4 + q
#pragma unroll
    for (int m = 0; m < 4; ++m) {
#pragma unroll
        for (int q = 0; q < 4; ++q) {
            const int row = R0 + m * 16 + g * 4 + q;
            if (row < M) {
                unsigned short* cp = C + (size_t)row * NHID + wc * 64 + l15;
#pragma unroll
                for (int n = 0; n < 4; ++n)
                    cp[n * 16] = f2bf(acc[m][n][q]);
            }
        }
    }
}

// ---------------- Pass A: bucket edges by dst>>8 (L2-local appends) ----------------
__global__ __launch_bounds__(256) void bucket_kernel(const int* __restrict__ src,
                                                     const int* __restrict__ dst,
                                                     const float* __restrict__ w,
                                                     int* __restrict__ bcur,
                                                     int2* __restrict__ bstage, int E) {
    const int e = blockIdx.x * 256 + threadIdx.x;
    if (e >= E) return;
    const int d = dst[e];
    const int b = d >> 8;
    const int pos = atomicAdd(&bcur[b * CURPAD], 1);
    if (pos < BCAP) {
        int2 p;
        p.x = src[e] | ((d & 255) << 17);   // src < 2^17, dst low 8 bits in [17..24]
        p.y = __float_as_int(w[e]);
        bstage[(size_t)b * BCAP + pos] = p;
    }
}

// ---------------- Pass B: per-bucket exact CSR via LDS hist/scan/cursors ----------------
__global__ __launch_bounds__(256) void csr_kernel(const int* __restrict__ bcur,
                                                  const int2* __restrict__ bstage,
                                                  int2* __restrict__ row_be,
                                                  int2* __restrict__ s_iw) {
    const int b = blockIdx.x;
    const int t = threadIdx.x;
    int cnt = bcur[b * CURPAD];
    if (cnt > BCAP) cnt = BCAP;
    const int sbase = b * BCAP;

    __shared__ int hist[256], scn[256], cur[256];
    hist[t] = 0;
    __syncthreads();
    for (int i = t; i < cnt; i += 256)
        atomicAdd(&hist[(bstage[sbase + i].x >> 17) & 255], 1);
    __syncthreads();
    scn[t] = hist[t];
    __syncthreads();
    for (int off = 1; off < 256; off <<= 1) {
        const int v = (t >= off) ? scn[t - off] : 0;
        __syncthreads();
        scn[t] += v;
        __syncthreads();
    }
    const int excl = scn[t] - hist[t];
    const int d = b * 256 + t;
    if (d < NNODES) {
        int2 be;
        be.x = sbase + excl;
        be.y = sbase + scn[t];
        row_be[d] = be;
    }
    cur[t] = excl;
    __syncthreads();
    for (int i = t; i < cnt; i += 256) {
        const int2 e = bstage[sbase + i];
        const int l = (e.x >> 17) & 255;
        const int p = atomicAdd(&cur[l], 1);
        int2 o;
        o.x = e.x & 0x1FFFF;
        o.y = e.y;
        s_iw[sbase + p] = o;
    }
}

// ---------------- Aggregate: one wave per node, bf16 gather, fp32 accumulate ----------------
__global__ __launch_bounds__(256) void aggregate_kernel(const unsigned short* __restrict__ hb,
                                                        const int2* __restrict__ row_be,
                                                        const int2* __restrict__ s_iw,
                                                        float* __restrict__ out, int n) {
    const int wid = (blockIdx.x * 256 + threadIdx.x) >> 6;
    if (wid >= n) return;
    const int lane = threadIdx.x & 63;
    const int2 be = row_be[wid];
    const int beg = be.x, end = be.y;
    const int boff = lane * 2;

    float ax = 0.f, ay = 0.f;
    int j = beg;
    for (; j + 4 <= end; j += 4) {
        const int2 e0 = s_iw[j], e1 = s_iw[j + 1], e2 = s_iw[j + 2], e3 = s_iw[j + 3];
        const unsigned int v0 = *reinterpret_cast<const unsigned int*>(hb + (size_t)e0.x * NHID + boff);
        const unsigned int v1 = *reinterpret_cast<const unsigned int*>(hb + (size_t)e1.x * NHID + boff);
        const unsigned int v2 = *reinterpret_cast<const unsigned int*>(hb + (size_t)e2.x * NHID + boff);
        const unsigned int v3 = *reinterpret_cast<const unsigned int*>(hb + (size_t)e3.x * NHID + boff);
        const float w0 = __int_as_float(e0.y), w1 = __int_as_float(e1.y);
        const float w2 = __int_as_float(e2.y), w3 = __int_as_float(e3.y);
        ax = fmaf(w0, bflo2f(v0), ax); ay = fmaf(w0, bfhi2f(v0), ay);
        ax = fmaf(w1, bflo2f(v1), ax); ay = fmaf(w1, bfhi2f(v1), ay);
        ax = fmaf(w2, bflo2f(v2), ax); ay = fmaf(w2, bfhi2f(v2), ay);
        ax = fmaf(w3, bflo2f(v3), ax); ay = fmaf(w3, bfhi2f(v3), ay);
    }
    for (; j < end; ++j) {
        const int2 e0 = s_iw[j];
        const unsigned int v0 = *reinterpret_cast<const unsigned int*>(hb + (size_t)e0.x * NHID + boff);
        const float w0 = __int_as_float(e0.y);
        ax = fmaf(w0, bflo2f(v0), ax);
        ay = fmaf(w0, bfhi2f(v0), ay);
    }
    float2 r;
    r.x = ax;
    r.y = ay;
    *reinterpret_cast<float2*>(out + (size_t)wid * NHID + boff) = r;
}

// ---------------- BN stats / finalize / final apply ----------------
__global__ __launch_bounds__(256) void stats_kernel(const float* __restrict__ h,
                                                    float* __restrict__ sums, int nrows) {
    const int col = threadIdx.x & 127;
    const int half = threadIdx.x >> 7;
    float s = 0.f, sq = 0.f;
    for (int r = blockIdx.x * 2 + half; r < nrows; r += gridDim.x * 2) {
        const float v = h[(size_t)r * NHID + col];
        s += v;
        sq += v * v;
    }
    __shared__ float ls[256], lq[256];
    ls[threadIdx.x] = s;
    lq[threadIdx.x] = sq;
    __syncthreads();
    if (threadIdx.x < 128) {
        atomicAdd(&sums[col], ls[threadIdx.x] + ls[threadIdx.x + 128]);
        atomicAdd(&sums[128 + col], lq[threadIdx.x] + lq[threadIdx.x + 128]);
    }
}

__global__ void finalize_kernel(const float* __restrict__ sums,
                                const float* __restrict__ gamma,
                                const float* __restrict__ beta,
                                float* __restrict__ ss) {
    const int c = threadIdx.x;
    const float invN = 1.0f / (float)NNODES;
    const float mean = sums[c] * invN;
    const float var = sums[128 + c] * invN - mean * mean;
    const float scale = gamma[c] * rsqrtf(var + EPS);
    ss[c] = scale;
    ss[128 + c] = beta[c] - mean * scale;
}

__global__ __launch_bounds__(256) void apply_f32_kernel(const float* __restrict__ in,
                                                        const float* __restrict__ ss,
                                                        float* __restrict__ out, int n4) {
    const int idx = blockIdx.x * 256 + threadIdx.x;
    if (idx >= n4) return;
    const int c = (idx & 31) * 4;
    const float4 v = reinterpret_cast<const float4*>(in)[idx];
    const float4 sc = *reinterpret_cast<const float4*>(ss + c);
    const float4 sh = *reinterpret_cast<const float4*>(ss + 128 + c);
    float4 r;
    r.x = fmaxf(fmaf(v.x, sc.x, sh.x), 0.f);
    r.y = fmaxf(fmaf(v.y, sc.y, sh.y), 0.f);
    r.z = fmaxf(fmaf(v.z, sc.z, sh.z), 0.f);
    r.w = fmaxf(fmaf(v.w, sc.w, sh.w), 0.f);
    reinterpret_cast<float4*>(out)[idx] = r;
}

extern "C" void kernel_launch(void* const* d_in, const int* in_sizes, int n_in,
                              void* d_out, int out_size, void* d_ws, size_t ws_size,
                              hipStream_t stream) {
    const float* x   = (const float*)d_in[0];
    const int*   ei  = (const int*)d_in[1];
    const float* ew  = (const float*)d_in[2];
    const float* W1  = (const float*)d_in[3];
    const float* g1  = (const float*)d_in[5];
    const float* be1 = (const float*)d_in[6];
    const float* W2  = (const float*)d_in[7];
    const float* g2  = (const float*)d_in[9];
    const float* be2 = (const float*)d_in[10];
    float* out = (float*)d_out;

    const int M = NNODES;
    const int E = in_sizes[2];
    const int* src = ei;
    const int* dst = ei + E;

    // workspace layout (~110 MB)
    unsigned short* hb = (unsigned short*)d_ws;               // M*128 bf16 (25.6 MB)
    float* agg   = (float*)(hb + (size_t)M * NHID);           // M*128 fp32 (51.2 MB)
    int2* bstage = (int2*)(agg + (size_t)M * NHID);           // NB*BCAP (16 MB)
    int2* s_iw   = bstage + (size_t)NB * BCAP;                // NB*BCAP (16 MB)
    int2* row_be = s_iw + (size_t)NB * BCAP;                  // N (800 KB)
    int* bcur    = (int*)(row_be + NNODES);                   // NB*CURPAD (25 KB)
    float* sums  = (float*)(bcur + NB * CURPAD);              // 256
    float* ss    = sums + 256;                                // 256

    const int gemm_grid = (M + 127) / 128;
    const int n4 = M * NHID / 4;
    const int app_grid = (n4 + 255) / 256;
    const int egrid = (E + 255) / 256;
    const int agg_grid = (M * 64 + 255) / 256;

    // ---- CSR build (shared by both layers) ----
    hipMemsetAsync(bcur, 0, (size_t)NB * CURPAD * sizeof(int), stream);
    bucket_kernel<<<egrid, 256, 0, stream>>>(src, dst, ew, bcur, bstage, E);
    csr_kernel<<<NB, 256, 0, stream>>>(bcur, bstage, row_be, s_iw);

    // ---- Layer 1 ----
    mfma_gemm<DIN, 0><<<gemm_grid, 256, 0, stream>>>(x, W1, nullptr, hb, M);
    aggregate_kernel<<<agg_grid, 256, 0, stream>>>(hb, row_be, s_iw, agg, M);
    hipMemsetAsync(sums, 0, 256 * sizeof(float), stream);
    stats_kernel<<<1024, 256, 0, stream>>>(agg, sums, M);
    finalize_kernel<<<1, 128, 0, stream>>>(sums, g1, be1, ss);

    // ---- Layer 2 (BN1+ReLU fused into GEMM2's A-load) ----
    mfma_gemm<NHID, 1><<<gemm_grid, 256, 0, stream>>>(agg, W2, ss, hb, M);
    aggregate_kernel<<<agg_grid, 256, 0, stream>>>(hb, row_be, s_iw, agg, M);
    hipMemsetAsync(sums, 0, 256 * sizeof(float), stream);
    stats_kernel<<<1024, 256, 0, stream>>>(agg, sums, M);
    finalize_kernel<<<1, 128, 0, stream>>>(sums, g2, be2, ss);
    apply_f32_kernel<<<app_grid, 256, 0, stream>>>(agg, ss, out, n4);
}

// Round 6
// 435.413 us; speedup vs baseline: 12.9154x; 1.0175x over previous
//
#include <hip/hip_runtime.h>
#include <hip/hip_bf16.h>

#define NNODES 100000
#define DIN    256
#define NHID   128
#define EPS    1e-5f
#define NB     ((NNODES + 255) >> 8)   // 391 buckets of 256 dst nodes
#define NCHUNK 8                       // edge chunks (one per XCD via blockIdx&7)
#define BCAP   704                     // per-(chunk,bucket) capacity: mean ~512, +8.5 sigma
#define SB     (NCHUNK * BCAP)         // per-bucket span in s_iw
#define CURPAD 16                      // counters padded to 64B

typedef __attribute__((ext_vector_type(8))) short short8v;  // 8 x bf16
typedef __attribute__((ext_vector_type(4))) float f32x4;

static __device__ __forceinline__ unsigned short f2bf(float v) {
    __hip_bfloat16 b = __float2bfloat16(v);
    return *reinterpret_cast<unsigned short*>(&b);
}
static __device__ __forceinline__ float bfhi2f(unsigned int u) {
    union { unsigned int i; float f; } x; x.i = u & 0xFFFF0000u; return x.f;
}
static __device__ __forceinline__ float bflo2f(unsigned int u) {
    union { unsigned int i; float f; } x; x.i = u << 16; return x.f;
}

// ---------------- MFMA GEMM: C[M][128] = A[M][K] @ W[K][128] ----------------
// MODE 0: A fp32 -> bf16 convert (layer-1: A = x)
// MODE 1: A fp32 + fused BN(scale/shift)+ReLU before convert (layer-2: A = agg)
template <int K, int MODE>
__global__ __launch_bounds__(256) void mfma_gemm(const float* __restrict__ Af,
                                                 const float* __restrict__ W,
                                                 const float* __restrict__ SS,
                                                 unsigned short* __restrict__ C, int M) {
    constexpr int LDW = K + 8;
    __shared__ unsigned short Wt[128 * LDW];   // W transposed: Wt[col][k]
    __shared__ float ssl[256];

    const int t = threadIdx.x;
    for (int i = t; i < K * 128; i += 256) {
        const int k = i >> 7;
        const int c = i & 127;
        Wt[c * LDW + k] = f2bf(W[i]);
    }
    if (MODE == 1 && t < 256) ssl[t] = SS[t];

    const int wid = t >> 6;
    const int lane = t & 63;
    const int wr = wid >> 1, wc = wid & 1;
    const int l15 = lane & 15, g = lane >> 4;
    const int R0 = blockIdx.x * 128 + wr * 64;

    f32x4 acc[4][4] = {};
    __syncthreads();

    for (int s = 0; s < K / 32; ++s) {
        short8v b[4];
#pragma unroll
        for (int n = 0; n < 4; ++n) {
            const int col = wc * 64 + n * 16 + l15;
            b[n] = *reinterpret_cast<const short8v*>(&Wt[col * LDW + s * 32 + g * 8]);
        }
        float sc[8], sh[8];
        if (MODE == 1) {
#pragma unroll
            for (int j = 0; j < 8; ++j) {
                sc[j] = ssl[s * 32 + g * 8 + j];
                sh[j] = ssl[128 + s * 32 + g * 8 + j];
            }
        }
        short8v a[4];
#pragma unroll
        for (int m = 0; m < 4; ++m) {
            int row = R0 + m * 16 + l15;
            row = row < M ? row : M - 1;   // clamp; pad rows discarded at store
            const float* p = Af + (size_t)row * K + s * 32 + g * 8;
            const float4 v0 = *reinterpret_cast<const float4*>(p);
            const float4 v1 = *reinterpret_cast<const float4*>(p + 4);
            float vv[8] = {v0.x, v0.y, v0.z, v0.w, v1.x, v1.y, v1.z, v1.w};
            short8v av;
#pragma unroll
            for (int j = 0; j < 8; ++j) {
                float y = vv[j];
                if (MODE == 1) y = fmaxf(fmaf(y, sc[j], sh[j]), 0.f);
                av[j] = (short)f2bf(y);
            }
            a[m] = av;
        }
#pragma unroll
        for (int m = 0; m < 4; ++m)
#pragma unroll
            for (int n = 0; n < 4; ++n)
                acc[m][n] = __builtin_amdgcn_mfma_f32_16x16x32_bf16(a[m], b[n], acc[m][n], 0, 0, 0);
    }

    // C/D layout: col = lane&15, row = (lane>>4)*4 + q
#pragma unroll
    for (int m = 0; m < 4; ++m) {
#pragma unroll
        for (int q = 0; q < 4; ++q) {
            const int row = R0 + m * 16 + g * 4 + q;
            if (row < M) {
                unsigned short* cp = C + (size_t)row * NHID + wc * 64 + l15;
#pragma unroll
                for (int n = 0; n < 4; ++n)
                    cp[n * 16] = f2bf(acc[m][n][q]);
            }
        }
    }
}

// ---------------- Pass A: bucket edges by dst>>8, XCD-chunked staging ----------------
// chunk = blockIdx&7: with round-robin block->XCD dispatch, each (chunk,bucket)
// frontier is written by one XCD only -> full lines accumulate in that XCD's L2.
__global__ __launch_bounds__(256) void bucket_kernel(const int* __restrict__ src,
                                                     const int* __restrict__ dst,
                                                     const float* __restrict__ w,
                                                     int* __restrict__ bcur,
                                                     int2* __restrict__ bstage, int E) {
    const int e = blockIdx.x * 256 + threadIdx.x;
    if (e >= E) return;
    const int ch = blockIdx.x & (NCHUNK - 1);
    const int d = dst[e];
    const int b = d >> 8;
    const int slot = ch * NB + b;
    const int pos = atomicAdd(&bcur[slot * CURPAD], 1);
    if (pos < BCAP) {
        int2 p;
        p.x = src[e] | ((d & 255) << 17);   // src < 2^17, dst low 8 bits in [17..24]
        p.y = __float_as_int(w[e]);
        bstage[(size_t)slot * BCAP + pos] = p;
    }
}

// ---------------- Pass B: per-bucket exact CSR via LDS hist/scan/cursors ----------------
__global__ __launch_bounds__(256) void csr_kernel(const int* __restrict__ bcur,
                                                  const int2* __restrict__ bstage,
                                                  int2* __restrict__ row_be,
                                                  int2* __restrict__ s_iw) {
    const int b = blockIdx.x;
    const int t = threadIdx.x;
    __shared__ int hist[256], scn[256], cur[256];
    __shared__ int cnts[NCHUNK];
    if (t < NCHUNK) {
        int c = bcur[(t * NB + b) * CURPAD];
        cnts[t] = c < BCAP ? c : BCAP;
    }
    hist[t] = 0;
    __syncthreads();
#pragma unroll
    for (int c = 0; c < NCHUNK; ++c) {
        const int2* sb = bstage + (size_t)(c * NB + b) * BCAP;
        const int cnt = cnts[c];
        for (int i = t; i < cnt; i += 256)
            atomicAdd(&hist[(sb[i].x >> 17) & 255], 1);
    }
    __syncthreads();
    scn[t] = hist[t];
    __syncthreads();
    for (int off = 1; off < 256; off <<= 1) {
        const int v = (t >= off) ? scn[t - off] : 0;
        __syncthreads();
        scn[t] += v;
        __syncthreads();
    }
    const int excl = scn[t] - hist[t];
    const int sbase = b * SB;
    const int d = b * 256 + t;
    if (d < NNODES) {
        int2 be;
        be.x = sbase + excl;
        be.y = sbase + scn[t];
        row_be[d] = be;
    }
    cur[t] = excl;
    __syncthreads();
#pragma unroll
    for (int c = 0; c < NCHUNK; ++c) {
        const int2* sb = bstage + (size_t)(c * NB + b) * BCAP;
        const int cnt = cnts[c];
        for (int i = t; i < cnt; i += 256) {
            const int2 e = sb[i];
            const int l = (e.x >> 17) & 255;
            const int p = atomicAdd(&cur[l], 1);
            int2 o;
            o.x = e.x & 0x1FFFF;
            o.y = e.y;
            s_iw[sbase + p] = o;
        }
    }
}

// ---------------- Aggregate: one wave per node, bf16 gather, fp32 accumulate ----------------
__global__ __launch_bounds__(256) void aggregate_kernel(const unsigned short* __restrict__ hb,
                                                        const int2* __restrict__ row_be,
                                                        const int2* __restrict__ s_iw,
                                                        float* __restrict__ out, int n) {
    const int wid = (blockIdx.x * 256 + threadIdx.x) >> 6;
    if (wid >= n) return;
    const int lane = threadIdx.x & 63;
    const int2 be = row_be[wid];
    const int beg = be.x, end = be.y;
    const int boff = lane * 2;

    float ax = 0.f, ay = 0.f;
    int j = beg;
    for (; j + 4 <= end; j += 4) {
        const int2 e0 = s_iw[j], e1 = s_iw[j + 1], e2 = s_iw[j + 2], e3 = s_iw[j + 3];
        const unsigned int v0 = *reinterpret_cast<const unsigned int*>(hb + (size_t)e0.x * NHID + boff);
        const unsigned int v1 = *reinterpret_cast<const unsigned int*>(hb + (size_t)e1.x * NHID + boff);
        const unsigned int v2 = *reinterpret_cast<const unsigned int*>(hb + (size_t)e2.x * NHID + boff);
        const unsigned int v3 = *reinterpret_cast<const unsigned int*>(hb + (size_t)e3.x * NHID + boff);
        const float w0 = __int_as_float(e0.y), w1 = __int_as_float(e1.y);
        const float w2 = __int_as_float(e2.y), w3 = __int_as_float(e3.y);
        ax = fmaf(w0, bflo2f(v0), ax); ay = fmaf(w0, bfhi2f(v0), ay);
        ax = fmaf(w1, bflo2f(v1), ax); ay = fmaf(w1, bfhi2f(v1), ay);
        ax = fmaf(w2, bflo2f(v2), ax); ay = fmaf(w2, bfhi2f(v2), ay);
        ax = fmaf(w3, bflo2f(v3), ax); ay = fmaf(w3, bfhi2f(v3), ay);
    }
    for (; j < end; ++j) {
        const int2 e0 = s_iw[j];
        const unsigned int v0 = *reinterpret_cast<const unsigned int*>(hb + (size_t)e0.x * NHID + boff);
        const float w0 = __int_as_float(e0.y);
        ax = fmaf(w0, bflo2f(v0), ax);
        ay = fmaf(w0, bfhi2f(v0), ay);
    }
    float2 r;
    r.x = ax;
    r.y = ay;
    *reinterpret_cast<float2*>(out + (size_t)wid * NHID + boff) = r;
}

// ---------------- BN stats / finalize / final apply ----------------
__global__ __launch_bounds__(256) void stats_kernel(const float* __restrict__ h,
                                                    float* __restrict__ sums, int nrows) {
    const int col = threadIdx.x & 127;
    const int half = threadIdx.x >> 7;
    float s = 0.f, sq = 0.f;
    for (int r = blockIdx.x * 2 + half; r < nrows; r += gridDim.x * 2) {
        const float v = h[(size_t)r * NHID + col];
        s += v;
        sq += v * v;
    }
    __shared__ float ls[256], lq[256];
    ls[threadIdx.x] = s;
    lq[threadIdx.x] = sq;
    __syncthreads();
    if (threadIdx.x < 128) {
        atomicAdd(&sums[col], ls[threadIdx.x] + ls[threadIdx.x + 128]);
        atomicAdd(&sums[128 + col], lq[threadIdx.x] + lq[threadIdx.x + 128]);
    }
}

__global__ void finalize_kernel(const float* __restrict__ sums,
                                const float* __restrict__ gamma,
                                const float* __restrict__ beta,
                                float* __restrict__ ss) {
    const int c = threadIdx.x;
    const float invN = 1.0f / (float)NNODES;
    const float mean = sums[c] * invN;
    const float var = sums[128 + c] * invN - mean * mean;
    const float scale = gamma[c] * rsqrtf(var + EPS);
    ss[c] = scale;
    ss[128 + c] = beta[c] - mean * scale;
}

__global__ __launch_bounds__(256) void apply_f32_kernel(const float* __restrict__ in,
                                                        const float* __restrict__ ss,
                                                        float* __restrict__ out, int n4) {
    const int idx = blockIdx.x * 256 + threadIdx.x;
    if (idx >= n4) return;
    const int c = (idx & 31) * 4;
    const float4 v = reinterpret_cast<const float4*>(in)[idx];
    const float4 sc = *reinterpret_cast<const float4*>(ss + c);
    const float4 sh = *reinterpret_cast<const float4*>(ss + 128 + c);
    float4 r;
    r.x = fmaxf(fmaf(v.x, sc.x, sh.x), 0.f);
    r.y = fmaxf(fmaf(v.y, sc.y, sh.y), 0.f);
    r.z = fmaxf(fmaf(v.z, sc.z, sh.z), 0.f);
    r.w = fmaxf(fmaf(v.w, sc.w, sh.w), 0.f);
    reinterpret_cast<float4*>(out)[idx] = r;
}

extern "C" void kernel_launch(void* const* d_in, const int* in_sizes, int n_in,
                              void* d_out, int out_size, void* d_ws, size_t ws_size,
                              hipStream_t stream) {
    const float* x   = (const float*)d_in[0];
    const int*   ei  = (const int*)d_in[1];
    const float* ew  = (const float*)d_in[2];
    const float* W1  = (const float*)d_in[3];
    const float* g1  = (const float*)d_in[5];
    const float* be1 = (const float*)d_in[6];
    const float* W2  = (const float*)d_in[7];
    const float* g2  = (const float*)d_in[9];
    const float* be2 = (const float*)d_in[10];
    float* out = (float*)d_out;

    const int M = NNODES;
    const int E = in_sizes[2];
    const int* src = ei;
    const int* dst = ei + E;

    // workspace layout (~113 MB)
    unsigned short* hb = (unsigned short*)d_ws;               // M*128 bf16 (25.6 MB)
    float* agg   = (float*)(hb + (size_t)M * NHID);           // M*128 fp32 (51.2 MB)
    int2* bstage = (int2*)(agg + (size_t)M * NHID);           // NCHUNK*NB*BCAP (17.6 MB)
    int2* s_iw   = bstage + (size_t)NCHUNK * NB * BCAP;       // NB*SB (17.6 MB)
    int2* row_be = s_iw + (size_t)NB * SB;                    // N (800 KB)
    int* bcur    = (int*)(row_be + NNODES);                   // NCHUNK*NB*CURPAD (200 KB)
    float* sums  = (float*)(bcur + NCHUNK * NB * CURPAD);     // 256
    float* ss    = sums + 256;                                // 256

    const int gemm_grid = (M + 127) / 128;
    const int n4 = M * NHID / 4;
    const int app_grid = (n4 + 255) / 256;
    const int egrid = (E + 255) / 256;
    const int agg_grid = (M * 64 + 255) / 256;

    // ---- CSR build (shared by both layers) ----
    hipMemsetAsync(bcur, 0, (size_t)NCHUNK * NB * CURPAD * sizeof(int), stream);
    bucket_kernel<<<egrid, 256, 0, stream>>>(src, dst, ew, bcur, bstage, E);
    csr_kernel<<<NB, 256, 0, stream>>>(bcur, bstage, row_be, s_iw);

    // ---- Layer 1 ----
    mfma_gemm<DIN, 0><<<gemm_grid, 256, 0, stream>>>(x, W1, nullptr, hb, M);
    aggregate_kernel<<<agg_grid, 256, 0, stream>>>(hb, row_be, s_iw, agg, M);
    hipMemsetAsync(sums, 0, 256 * sizeof(float), stream);
    stats_kernel<<<1024, 256, 0, stream>>>(agg, sums, M);
    finalize_kernel<<<1, 128, 0, stream>>>(sums, g1, be1, ss);

    // ---- Layer 2 (BN1+ReLU fused into GEMM2's A-load) ----
    mfma_gemm<NHID, 1><<<gemm_grid, 256, 0, stream>>>(agg, W2, ss, hb, M);
    aggregate_kernel<<<agg_grid, 256, 0, stream>>>(hb, row_be, s_iw, agg, M);
    hipMemsetAsync(sums, 0, 256 * sizeof(float), stream);
    stats_kernel<<<1024, 256, 0, stream>>>(agg, sums, M);
    finalize_kernel<<<1, 128, 0, stream>>>(sums, g2, be2, ss);
    apply_f32_kernel<<<app_grid, 256, 0, stream>>>(agg, ss, out, n4);
}